// Round 13
// baseline (454.483 us; speedup 1.0000x reference)
//
#include <hip/hip_runtime.h>

typedef unsigned short u16;
typedef unsigned int u32;
typedef __attribute__((ext_vector_type(8))) short bf16x8;
typedef __attribute__((ext_vector_type(4))) float f32x4;

__device__ __forceinline__ u16 f2bf(float f) {
  u32 u = __float_as_uint(f);
  u32 r = (u + 0x7FFFu + ((u >> 16) & 1u)) >> 16;  // RTNE
  return (u16)r;
}

__device__ __forceinline__ void gl_lds16(const u16* g, u16* l) {
  __builtin_amdgcn_global_load_lds(
      (const __attribute__((address_space(1))) u32*)g,
      (__attribute__((address_space(3))) u32*)l, 16, 0, 0);
}

// ---------------- prep: U fp32 -> bf16 ----------------
__global__ __launch_bounds__(256) void cvt_bf16(const float* __restrict__ src,
                                                u16* __restrict__ dst, int n4) {
  int g = blockIdx.x * 256 + threadIdx.x;
  if (g < n4) {
    float4 v = ((const float4*)src)[g];
    ushort4 o;
    o.x = f2bf(v.x); o.y = f2bf(v.y); o.z = f2bf(v.z); o.w = f2bf(v.w);
    ((ushort4*)dst)[g] = o;
  }
}

// ---------------- prep: x fp32 -> Xb bf16 [b][l][d] and XT bf16 [b][d][l] ----------------
__global__ __launch_bounds__(256) void prep_x(const float* __restrict__ x,
                                              u16* __restrict__ Xb,
                                              u16* __restrict__ XT) {
  __shared__ u16 t[32][33];
  const int b = blockIdx.z;
  const int l0 = blockIdx.y * 32;
  const int d0 = blockIdx.x * 32;
  const int j = threadIdx.x & 31;
  const int t5 = threadIdx.x >> 5;
#pragma unroll
  for (int r = 0; r < 4; r++) {
    int i = r * 8 + t5;
    float v = x[((size_t)b * 2048 + l0 + i) * 512 + d0 + j];
    u16 h = f2bf(v);
    t[i][j] = h;
    Xb[((size_t)b * 2048 + l0 + i) * 512 + d0 + j] = h;
  }
  __syncthreads();
#pragma unroll
  for (int r = 0; r < 4; r++) {
    int i = r * 8 + t5;
    XT[((size_t)b * 512 + d0 + i) * 2048 + l0 + j] = t[j][i];
  }
}

__global__ __launch_bounds__(256) void zero_f32(float* __restrict__ p, int n) {
  int g = blockIdx.x * 256 + threadIdx.x;
  if (g < n) p[g] = 0.f;
}

// ---------------- gemm1: P[b] = bf16(exp(U @ x_b^T)), rowsum -> z ----------------
// R12 main loop (128x128 tile, BK=64, 4 waves 2x2, swizzled single-buffer LDS,
// 2-barrier K-loop, 4 blocks/CU). Epilogue: exp in regs -> rowsum via 16-lane
// shfl_xor + atomicAdd (R7-verified) -> bf16 tile into dead LDS -> coalesced
// dwordx4 stores (R12-verified).
__global__ __launch_bounds__(256, 4)
void gemm1k(const u16* __restrict__ A, const u16* __restrict__ B,
            u16* __restrict__ P, float* __restrict__ z, int nt,
            size_t Bb_str, size_t Cb_str, int gx, int gy) {
  __shared__ u16 lds[16384];   // A tile @0, B tile @8192; epilogue: 128x128 u16

  const int nwg = gx * gy * gridDim.z;
  const int orig = blockIdx.x + gx * (blockIdx.y + gy * blockIdx.z);
  const int cpx = nwg >> 3;
  const int nid = (orig & 7) * cpx + (orig >> 3);
  const int bxi = nid % gx;
  const int byi = (nid / gx) % gy;
  const int bzi = nid / (gx * gy);
  const int m0 = byi * 128, n0 = bxi * 128;

  const int tid = threadIdx.x;
  const int l = tid & 63;
  const int w = tid >> 6;
  const int wy = w >> 1, wx = w & 1;

  // staging (write side; inverse-swizzled global source)
  const int rowS = tid >> 3;
  const int cS = ((tid & 7) << 4) ^ ((rowS & 7) << 4);
  const u16* srcA0 = A + (size_t)(m0 + rowS) * 512 + (cS >> 1);
  const u16* srcB0 = B + (size_t)bzi * Bb_str + (size_t)(n0 + rowS) * 512 + (cS >> 1);
  const size_t rsk = (size_t)32 * 512;

  // read side (swizzled ds_read addresses)
  const int fr = l & 15;
  const int X = (fr & 7) << 4;
  const int kb = (l >> 4) << 4;
  const int swz0 = (kb ^ X) >> 1;
  const int swz1 = ((64 + kb) ^ X) >> 1;
  const int aRow = (wy * 64 + fr) * 64;
  const int bRow = (wx * 64 + fr) * 64;

  f32x4 acc[4][4] = {};

  for (int t = 0; t < nt; ++t) {
#pragma unroll
    for (int j = 0; j < 4; j++) {
      gl_lds16(srcA0 + j * rsk + t * 64, &lds[tid * 8 + j * 2048]);
      gl_lds16(srcB0 + j * rsk + t * 64, &lds[8192 + tid * 8 + j * 2048]);
    }
    __syncthreads();
#pragma unroll
    for (int ks = 0; ks < 2; ks++) {
      const int swz = ks ? swz1 : swz0;
      bf16x8 bfr[4], afr[4];
#pragma unroll
      for (int n = 0; n < 4; n++) bfr[n] = *(const bf16x8*)&lds[8192 + bRow + n * 1024 + swz];
#pragma unroll
      for (int m = 0; m < 4; m++) afr[m] = *(const bf16x8*)&lds[aRow + m * 1024 + swz];
#pragma unroll
      for (int m = 0; m < 4; m++)
#pragma unroll
        for (int n = 0; n < 4; n++)
          acc[m][n] = __builtin_amdgcn_mfma_f32_16x16x32_bf16(
              afr[m], bfr[n], acc[m][n], 0, 0, 0);
    }
    __syncthreads();
  }

  // ---- epilogue: exp -> rowsum(shfl+atomic) + bf16 tile in LDS -> coalesced stores ----
  float* zb = z + (size_t)bzi * 8192;
  const int rq = (l >> 4) * 4;  // C/D: col=lane&15, row=(lane>>4)*4+reg
#pragma unroll
  for (int m = 0; m < 4; m++) {
    const int lr0 = wy * 64 + m * 16 + rq;
    float rs[4] = {0.f, 0.f, 0.f, 0.f};
#pragma unroll
    for (int n = 0; n < 4; n++) {
      const int lc = wx * 64 + n * 16 + fr;
#pragma unroll
      for (int r = 0; r < 4; r++) {
        const float e = __expf(acc[m][n][r]);
        lds[(lr0 + r) * 128 + lc] = f2bf(e);
        rs[r] += e;
      }
    }
#pragma unroll
    for (int s = 1; s < 16; s <<= 1)
#pragma unroll
      for (int r = 0; r < 4; r++) rs[r] += __shfl_xor(rs[r], s);
    if (fr == 0) {
#pragma unroll
      for (int r = 0; r < 4; r++) atomicAdd(&zb[m0 + lr0 + r], rs[r]);
    }
  }
  __syncthreads();
  u16* Pb = P + (size_t)bzi * Cb_str;
#pragma unroll
  for (int k = 0; k < 8; k++) {
    const int row = k * 16 + (tid >> 4);
    const int cu = (tid & 15) * 8;
    *(uint4*)&Pb[(size_t)(m0 + row) * 2048 + n0 + cu] = *(const uint4*)&lds[row * 128 + cu];
  }
}

// ---------------- gemm2: out[b] = (P[b] @ XT_b^T) / z[b] (R7-exact) ----------------
__global__ __launch_bounds__(256, 4)
void gemm2k(const u16* __restrict__ A, const u16* __restrict__ B,
            float* __restrict__ Cout, const float* __restrict__ z,
            int Kstride, int nt, int N,
            size_t Ab_str, size_t Bb_str, size_t Cb_str, int gx, int gy) {
  __shared__ u16 lds[16384];
  __shared__ float rz_lds[128];

  const int nwg = gx * gy * gridDim.z;
  const int orig = blockIdx.x + gx * (blockIdx.y + gy * blockIdx.z);
  const int cpx = nwg >> 3;
  const int nid = (orig & 7) * cpx + (orig >> 3);
  const int bxi = nid % gx;
  const int byi = (nid / gx) % gy;
  const int bzi = nid / (gx * gy);
  const int m0 = byi * 128, n0 = bxi * 128;

  const u16* Ab = A + (size_t)bzi * Ab_str;
  const u16* Bb = B + (size_t)bzi * Bb_str;

  const int tid = threadIdx.x;
  const int l = tid & 63;
  const int w = tid >> 6;
  const int wy = w >> 1, wx = w & 1;

  const int rowS = tid >> 3;
  const int cS = ((tid & 7) << 4) ^ ((rowS & 7) << 4);
  const u16* srcA0 = Ab + (size_t)(m0 + rowS) * Kstride + (cS >> 1);
  const u16* srcB0 = Bb + (size_t)(n0 + rowS) * Kstride + (cS >> 1);
  const size_t rsk = (size_t)32 * Kstride;

  const int fr = l & 15;
  const int X = (fr & 7) << 4;
  const int kb = (l >> 4) << 4;
  const int swz0 = (kb ^ X) >> 1;
  const int swz1 = ((64 + kb) ^ X) >> 1;
  const int aRow = (wy * 64 + fr) * 64;
  const int bRow = (wx * 64 + fr) * 64;

  if (tid < 128) rz_lds[tid] = 1.f / z[(size_t)bzi * 8192 + m0 + tid];

  f32x4 acc[4][4] = {};

  for (int t = 0; t < nt; ++t) {
#pragma unroll
    for (int j = 0; j < 4; j++) {
      gl_lds16(srcA0 + j * rsk + t * 64, &lds[tid * 8 + j * 2048]);
      gl_lds16(srcB0 + j * rsk + t * 64, &lds[8192 + tid * 8 + j * 2048]);
    }
    __syncthreads();
#pragma unroll
    for (int ks = 0; ks < 2; ks++) {
      const int swz = ks ? swz1 : swz0;
      bf16x8 bfr[4], afr[4];
#pragma unroll
      for (int n = 0; n < 4; n++) bfr[n] = *(const bf16x8*)&lds[8192 + bRow + n * 1024 + swz];
#pragma unroll
      for (int m = 0; m < 4; m++) afr[m] = *(const bf16x8*)&lds[aRow + m * 1024 + swz];
#pragma unroll
      for (int m = 0; m < 4; m++)
#pragma unroll
        for (int n = 0; n < 4; n++)
          acc[m][n] = __builtin_amdgcn_mfma_f32_16x16x32_bf16(
              afr[m], bfr[n], acc[m][n], 0, 0, 0);
    }
    __syncthreads();
  }

  const int rq = (l >> 4) * 4;
#pragma unroll
  for (int m = 0; m < 4; m++) {
    const int lrow = wy * 64 + m * 16 + rq;
    const int grow = m0 + lrow;
#pragma unroll
    for (int n = 0; n < 4; n++) {
      const int col = n0 + wx * 64 + n * 16 + fr;
#pragma unroll
      for (int r = 0; r < 4; r++)
        Cout[(size_t)bzi * Cb_str + (size_t)(grow + r) * N + col] =
            acc[m][n][r] * rz_lds[lrow + r];
    }
  }
}

// B=8, L=2048, D=512, Y=8192
extern "C" void kernel_launch(void* const* d_in, const int* in_sizes, int n_in,
                              void* d_out, int out_size, void* d_ws, size_t ws_size,
                              hipStream_t stream) {
  const float* x = (const float*)d_in[0];   // [8][2048][512]
  const float* U = (const float*)d_in[1];   // [8192][512]
  if (n_in >= 2 && in_sizes[0] == 8192 * 512) {
    x = (const float*)d_in[1];
    U = (const float*)d_in[0];
  }
  float* out = (float*)d_out;               // [8][8192][512]
  char* ws = (char*)d_ws;

  // ws layout (bytes)
  u16* Ub = (u16*)ws;                       // 8 MiB
  u16* Xb = (u16*)(ws + 8388608);           // 16 MiB
  u16* XT = (u16*)(ws + 25165824);          // 16 MiB
  u16* P  = (u16*)(ws + 41943040);          // all-batch: 256 MiB
  const size_t need_all = 41943040ull + 268435456ull + 262144ull;

  cvt_bf16<<<4096, 256, 0, stream>>>(U, Ub, (8192 * 512) / 4);
  prep_x<<<dim3(16, 64, 8), 256, 0, stream>>>(x, Xb, XT);

  if (ws_size >= need_all) {
    float* z = (float*)(ws + 41943040 + 268435456);
    zero_f32<<<256, 256, 0, stream>>>(z, 8 * 8192);
    // P[b] = exp(U @ x_b^T), fused rowsum -> z[b]: M=8192, N=2048, K=512
    gemm1k<<<dim3(16, 64, 8), 256, 0, stream>>>(
        Ub, Xb, P, z, 8, (size_t)2048 * 512, (size_t)8192 * 2048, 16, 64);
    // out[b] = (P[b] @ XT_b^T) / z[b]: M=8192, N=512, K=2048
    gemm2k<<<dim3(4, 64, 8), 256, 0, stream>>>(
        P, XT, out, z, 2048, 32, 512,
        (size_t)8192 * 2048, (size_t)512 * 2048, (size_t)8192 * 512, 4, 64);
  } else {
    // fallback: per-batch P (32 MiB)
    float* z = (float*)(ws + 41943040 + 33554432);
    zero_f32<<<256, 256, 0, stream>>>(z, 8 * 8192);
    for (int b = 0; b < 8; b++) {
      gemm1k<<<dim3(16, 64, 1), 256, 0, stream>>>(
          Ub, Xb + (size_t)b * 2048 * 512, P, z + b * 8192, 8, 0, 0, 16, 64);
      gemm2k<<<dim3(4, 64, 1), 256, 0, stream>>>(
          P, XT + (size_t)b * 512 * 2048, out + (size_t)b * 8192 * 512,
          z + b * 8192, 2048, 32, 512, 0, 0, 0, 4, 64);
    }
  }
}

// Round 14
// 396.865 us; speedup vs baseline: 1.1452x; 1.1452x over previous
//
#include <hip/hip_runtime.h>

typedef unsigned short u16;
typedef unsigned int u32;
typedef __attribute__((ext_vector_type(8))) short bf16x8;
typedef __attribute__((ext_vector_type(4))) float f32x4;

__device__ __forceinline__ u16 f2bf(float f) {
  u32 u = __float_as_uint(f);
  u32 r = (u + 0x7FFFu + ((u >> 16) & 1u)) >> 16;  // RTNE
  return (u16)r;
}

__device__ __forceinline__ void gl_lds16(const u16* g, u16* l) {
  __builtin_amdgcn_global_load_lds(
      (const __attribute__((address_space(1))) u32*)g,
      (__attribute__((address_space(3))) u32*)l, 16, 0, 0);
}

// ---------------- prep: U fp32 -> bf16 ----------------
__global__ __launch_bounds__(256) void cvt_bf16(const float* __restrict__ src,
                                                u16* __restrict__ dst, int n4) {
  int g = blockIdx.x * 256 + threadIdx.x;
  if (g < n4) {
    float4 v = ((const float4*)src)[g];
    ushort4 o;
    o.x = f2bf(v.x); o.y = f2bf(v.y); o.z = f2bf(v.z); o.w = f2bf(v.w);
    ((ushort4*)dst)[g] = o;
  }
}

// ---------------- prep: x fp32 -> Xb bf16 [b][l][d] and XT bf16 [b][d][l] ----------------
__global__ __launch_bounds__(256) void prep_x(const float* __restrict__ x,
                                              u16* __restrict__ Xb,
                                              u16* __restrict__ XT) {
  __shared__ u16 t[32][33];
  const int b = blockIdx.z;
  const int l0 = blockIdx.y * 32;
  const int d0 = blockIdx.x * 32;
  const int j = threadIdx.x & 31;
  const int t5 = threadIdx.x >> 5;
#pragma unroll
  for (int r = 0; r < 4; r++) {
    int i = r * 8 + t5;
    float v = x[((size_t)b * 2048 + l0 + i) * 512 + d0 + j];
    u16 h = f2bf(v);
    t[i][j] = h;
    Xb[((size_t)b * 2048 + l0 + i) * 512 + d0 + j] = h;
  }
  __syncthreads();
#pragma unroll
  for (int r = 0; r < 4; r++) {
    int i = r * 8 + t5;
    XT[((size_t)b * 512 + d0 + i) * 2048 + l0 + j] = t[j][i];
  }
}

__global__ __launch_bounds__(256) void zero_f32(float* __restrict__ p, int n) {
  int g = blockIdx.x * 256 + threadIdx.x;
  if (g < n) p[g] = 0.f;
}

// ---------------- gemm1: P[b] = bf16(exp(U @ x_b^T)), tail rowsum -> z ----------------
// R12-exact main loop and epilogue (128x128 tile, BK=64, 4 waves 2x2, swizzled
// single-buffer LDS, 2-barrier K-loop, 4 blocks/CU; exp->bf16 tile in dead LDS
// -> coalesced dwordx4 stores). NEW: z partial sums computed from the SAME
// uint4 each thread stores (8 VALU + 4 shfl + tail atomicAdd, after all
// barriers, fire-and-forget -- R13's pre-barrier 64-shfl version regressed).
__global__ __launch_bounds__(256, 4)
void gemm1k(const u16* __restrict__ A, const u16* __restrict__ B,
            u16* __restrict__ P, float* __restrict__ z, int nt,
            size_t Bb_str, size_t Cb_str, int gx, int gy) {
  __shared__ u16 lds[16384];   // A tile @0, B tile @8192; epilogue: 128x128 u16

  const int nwg = gx * gy * gridDim.z;
  const int orig = blockIdx.x + gx * (blockIdx.y + gy * blockIdx.z);
  const int cpx = nwg >> 3;
  const int nid = (orig & 7) * cpx + (orig >> 3);
  const int bxi = nid % gx;
  const int byi = (nid / gx) % gy;
  const int bzi = nid / (gx * gy);
  const int m0 = byi * 128, n0 = bxi * 128;

  const int tid = threadIdx.x;
  const int l = tid & 63;
  const int w = tid >> 6;
  const int wy = w >> 1, wx = w & 1;

  // staging (write side; inverse-swizzled global source)
  const int rowS = tid >> 3;
  const int cS = ((tid & 7) << 4) ^ ((rowS & 7) << 4);
  const u16* srcA0 = A + (size_t)(m0 + rowS) * 512 + (cS >> 1);
  const u16* srcB0 = B + (size_t)bzi * Bb_str + (size_t)(n0 + rowS) * 512 + (cS >> 1);
  const size_t rsk = (size_t)32 * 512;

  // read side (swizzled ds_read addresses)
  const int fr = l & 15;
  const int X = (fr & 7) << 4;
  const int kb = (l >> 4) << 4;
  const int swz0 = (kb ^ X) >> 1;
  const int swz1 = ((64 + kb) ^ X) >> 1;
  const int aRow = (wy * 64 + fr) * 64;
  const int bRow = (wx * 64 + fr) * 64;

  f32x4 acc[4][4] = {};

  for (int t = 0; t < nt; ++t) {
#pragma unroll
    for (int j = 0; j < 4; j++) {
      gl_lds16(srcA0 + j * rsk + t * 64, &lds[tid * 8 + j * 2048]);
      gl_lds16(srcB0 + j * rsk + t * 64, &lds[8192 + tid * 8 + j * 2048]);
    }
    __syncthreads();
#pragma unroll
    for (int ks = 0; ks < 2; ks++) {
      const int swz = ks ? swz1 : swz0;
      bf16x8 bfr[4], afr[4];
#pragma unroll
      for (int n = 0; n < 4; n++) bfr[n] = *(const bf16x8*)&lds[8192 + bRow + n * 1024 + swz];
#pragma unroll
      for (int m = 0; m < 4; m++) afr[m] = *(const bf16x8*)&lds[aRow + m * 1024 + swz];
#pragma unroll
      for (int m = 0; m < 4; m++)
#pragma unroll
        for (int n = 0; n < 4; n++)
          acc[m][n] = __builtin_amdgcn_mfma_f32_16x16x32_bf16(
              afr[m], bfr[n], acc[m][n], 0, 0, 0);
    }
    __syncthreads();
  }

  // ---- epilogue (R12-exact): exp -> bf16 tile in LDS -> coalesced stores ----
  const int rq = (l >> 4) * 4;  // C/D: col=lane&15, row=(lane>>4)*4+reg
#pragma unroll
  for (int m = 0; m < 4; m++) {
    const int lr0 = wy * 64 + m * 16 + rq;
#pragma unroll
    for (int n = 0; n < 4; n++) {
      const int lc = wx * 64 + n * 16 + fr;
#pragma unroll
      for (int r = 0; r < 4; r++)
        lds[(lr0 + r) * 128 + lc] = f2bf(__expf(acc[m][n][r]));
    }
  }
  __syncthreads();
  u16* Pb = P + (size_t)bzi * Cb_str;
  float* zb = z + (size_t)bzi * 8192;
#pragma unroll
  for (int k = 0; k < 8; k++) {
    const int row = k * 16 + (tid >> 4);
    const int cu = (tid & 15) * 8;
    const uint4 v = *(const uint4*)&lds[row * 128 + cu];
    *(uint4*)&Pb[(size_t)(m0 + row) * 2048 + n0 + cu] = v;
    // z partial: sum the 8 bf16 values just stored (all barriers already done)
    float s = __uint_as_float(v.x << 16) + __uint_as_float(v.x & 0xffff0000u) +
              __uint_as_float(v.y << 16) + __uint_as_float(v.y & 0xffff0000u) +
              __uint_as_float(v.z << 16) + __uint_as_float(v.z & 0xffff0000u) +
              __uint_as_float(v.w << 16) + __uint_as_float(v.w & 0xffff0000u);
    s += __shfl_xor(s, 1);
    s += __shfl_xor(s, 2);
    s += __shfl_xor(s, 4);
    s += __shfl_xor(s, 8);
    if ((l & 15) == 0) atomicAdd(&zb[m0 + row], s);
  }
}

// ---------------- gemm2: out[b] = (P[b] @ XT_b^T) / z[b] (R7/R13-exact) ----------------
__global__ __launch_bounds__(256, 4)
void gemm2k(const u16* __restrict__ A, const u16* __restrict__ B,
            float* __restrict__ Cout, const float* __restrict__ z,
            int Kstride, int nt, int N,
            size_t Ab_str, size_t Bb_str, size_t Cb_str, int gx, int gy) {
  __shared__ u16 lds[16384];
  __shared__ float rz_lds[128];

  const int nwg = gx * gy * gridDim.z;
  const int orig = blockIdx.x + gx * (blockIdx.y + gy * blockIdx.z);
  const int cpx = nwg >> 3;
  const int nid = (orig & 7) * cpx + (orig >> 3);
  const int bxi = nid % gx;
  const int byi = (nid / gx) % gy;
  const int bzi = nid / (gx * gy);
  const int m0 = byi * 128, n0 = bxi * 128;

  const u16* Ab = A + (size_t)bzi * Ab_str;
  const u16* Bb = B + (size_t)bzi * Bb_str;

  const int tid = threadIdx.x;
  const int l = tid & 63;
  const int w = tid >> 6;
  const int wy = w >> 1, wx = w & 1;

  const int rowS = tid >> 3;
  const int cS = ((tid & 7) << 4) ^ ((rowS & 7) << 4);
  const u16* srcA0 = Ab + (size_t)(m0 + rowS) * Kstride + (cS >> 1);
  const u16* srcB0 = Bb + (size_t)(n0 + rowS) * Kstride + (cS >> 1);
  const size_t rsk = (size_t)32 * Kstride;

  const int fr = l & 15;
  const int X = (fr & 7) << 4;
  const int kb = (l >> 4) << 4;
  const int swz0 = (kb ^ X) >> 1;
  const int swz1 = ((64 + kb) ^ X) >> 1;
  const int aRow = (wy * 64 + fr) * 64;
  const int bRow = (wx * 64 + fr) * 64;

  if (tid < 128) rz_lds[tid] = 1.f / z[(size_t)bzi * 8192 + m0 + tid];

  f32x4 acc[4][4] = {};

  for (int t = 0; t < nt; ++t) {
#pragma unroll
    for (int j = 0; j < 4; j++) {
      gl_lds16(srcA0 + j * rsk + t * 64, &lds[tid * 8 + j * 2048]);
      gl_lds16(srcB0 + j * rsk + t * 64, &lds[8192 + tid * 8 + j * 2048]);
    }
    __syncthreads();
#pragma unroll
    for (int ks = 0; ks < 2; ks++) {
      const int swz = ks ? swz1 : swz0;
      bf16x8 bfr[4], afr[4];
#pragma unroll
      for (int n = 0; n < 4; n++) bfr[n] = *(const bf16x8*)&lds[8192 + bRow + n * 1024 + swz];
#pragma unroll
      for (int m = 0; m < 4; m++) afr[m] = *(const bf16x8*)&lds[aRow + m * 1024 + swz];
#pragma unroll
      for (int m = 0; m < 4; m++)
#pragma unroll
        for (int n = 0; n < 4; n++)
          acc[m][n] = __builtin_amdgcn_mfma_f32_16x16x32_bf16(
              afr[m], bfr[n], acc[m][n], 0, 0, 0);
    }
    __syncthreads();
  }

  const int rq = (l >> 4) * 4;
#pragma unroll
  for (int m = 0; m < 4; m++) {
    const int lrow = wy * 64 + m * 16 + rq;
    const int grow = m0 + lrow;
#pragma unroll
    for (int n = 0; n < 4; n++) {
      const int col = n0 + wx * 64 + n * 16 + fr;
#pragma unroll
      for (int r = 0; r < 4; r++)
        Cout[(size_t)bzi * Cb_str + (size_t)(grow + r) * N + col] =
            acc[m][n][r] * rz_lds[lrow + r];
    }
  }
}

// B=8, L=2048, D=512, Y=8192
extern "C" void kernel_launch(void* const* d_in, const int* in_sizes, int n_in,
                              void* d_out, int out_size, void* d_ws, size_t ws_size,
                              hipStream_t stream) {
  const float* x = (const float*)d_in[0];   // [8][2048][512]
  const float* U = (const float*)d_in[1];   // [8192][512]
  if (n_in >= 2 && in_sizes[0] == 8192 * 512) {
    x = (const float*)d_in[1];
    U = (const float*)d_in[0];
  }
  float* out = (float*)d_out;               // [8][8192][512]
  char* ws = (char*)d_ws;

  // ws layout (bytes)
  u16* Ub = (u16*)ws;                       // 8 MiB
  u16* Xb = (u16*)(ws + 8388608);           // 16 MiB
  u16* XT = (u16*)(ws + 25165824);          // 16 MiB
  u16* P  = (u16*)(ws + 41943040);          // all-batch: 256 MiB
  const size_t need_all = 41943040ull + 268435456ull + 262144ull;

  cvt_bf16<<<4096, 256, 0, stream>>>(U, Ub, (8192 * 512) / 4);
  prep_x<<<dim3(16, 64, 8), 256, 0, stream>>>(x, Xb, XT);

  if (ws_size >= need_all) {
    float* z = (float*)(ws + 41943040 + 268435456);
    zero_f32<<<256, 256, 0, stream>>>(z, 8 * 8192);
    // P[b] = exp(U @ x_b^T), tail rowsum -> z[b]: M=8192, N=2048, K=512
    gemm1k<<<dim3(16, 64, 8), 256, 0, stream>>>(
        Ub, Xb, P, z, 8, (size_t)2048 * 512, (size_t)8192 * 2048, 16, 64);
    // out[b] = (P[b] @ XT_b^T) / z[b]: M=8192, N=512, K=2048
    gemm2k<<<dim3(4, 64, 8), 256, 0, stream>>>(
        P, XT, out, z, 2048, 32, 512,
        (size_t)8192 * 2048, (size_t)512 * 2048, (size_t)8192 * 512, 4, 64);
  } else {
    // fallback: per-batch P (32 MiB)
    float* z = (float*)(ws + 41943040 + 33554432);
    zero_f32<<<256, 256, 0, stream>>>(z, 8 * 8192);
    for (int b = 0; b < 8; b++) {
      gemm1k<<<dim3(16, 64, 1), 256, 0, stream>>>(
          Ub, Xb + (size_t)b * 2048 * 512, P, z + b * 8192, 8, 0, 0, 16, 64);
      gemm2k<<<dim3(4, 64, 1), 256, 0, stream>>>(
          P, XT + (size_t)b * 512 * 2048, out + (size_t)b * 8192 * 512,
          z + b * 8192, 2048, 32, 512, 0, 0, 0, 4, 64);
    }
  }
}

// Round 15
// 357.821 us; speedup vs baseline: 1.2701x; 1.1091x over previous
//
#include <hip/hip_runtime.h>

typedef unsigned short u16;
typedef unsigned int u32;
typedef __attribute__((ext_vector_type(8))) short bf16x8;
typedef __attribute__((ext_vector_type(4))) float f32x4;

__device__ __forceinline__ u16 f2bf(float f) {
  u32 u = __float_as_uint(f);
  u32 r = (u + 0x7FFFu + ((u >> 16) & 1u)) >> 16;  // RTNE
  return (u16)r;
}

__device__ __forceinline__ void gl_lds16(const u16* g, u16* l) {
  __builtin_amdgcn_global_load_lds(
      (const __attribute__((address_space(1))) u32*)g,
      (__attribute__((address_space(3))) u32*)l, 16, 0, 0);
}

// sum of 8 bf16 values in a fragment (4 u32s), f32 accumulate
__device__ __forceinline__ float sumfrag(bf16x8 v) {
  const u32* p = (const u32*)&v;
  float s = 0.f;
#pragma unroll
  for (int i = 0; i < 4; i++) {
    s += __uint_as_float(p[i] << 16);
    s += __uint_as_float(p[i] & 0xffff0000u);
  }
  return s;
}

// ---------------- prep: U fp32 -> bf16 ----------------
__global__ __launch_bounds__(256) void cvt_bf16(const float* __restrict__ src,
                                                u16* __restrict__ dst, int n4) {
  int g = blockIdx.x * 256 + threadIdx.x;
  if (g < n4) {
    float4 v = ((const float4*)src)[g];
    ushort4 o;
    o.x = f2bf(v.x); o.y = f2bf(v.y); o.z = f2bf(v.z); o.w = f2bf(v.w);
    ((ushort4*)dst)[g] = o;
  }
}

// ---------------- prep: x fp32 -> Xb bf16 [b][l][d] and XT bf16 [b][d][l] ----------------
__global__ __launch_bounds__(256) void prep_x(const float* __restrict__ x,
                                              u16* __restrict__ Xb,
                                              u16* __restrict__ XT) {
  __shared__ u16 t[32][33];
  const int b = blockIdx.z;
  const int l0 = blockIdx.y * 32;
  const int d0 = blockIdx.x * 32;
  const int j = threadIdx.x & 31;
  const int t5 = threadIdx.x >> 5;
#pragma unroll
  for (int r = 0; r < 4; r++) {
    int i = r * 8 + t5;
    float v = x[((size_t)b * 2048 + l0 + i) * 512 + d0 + j];
    u16 h = f2bf(v);
    t[i][j] = h;
    Xb[((size_t)b * 2048 + l0 + i) * 512 + d0 + j] = h;
  }
  __syncthreads();
#pragma unroll
  for (int r = 0; r < 4; r++) {
    int i = r * 8 + t5;
    XT[((size_t)b * 512 + d0 + i) * 2048 + l0 + j] = t[j][i];
  }
}

// ---------------- gemm1: P[b] = bf16(exp(U @ x_b^T))  (R12-exact, NO rowsum) ----------------
// 128x128 tile, BK=64, 4 waves 2x2, swizzled single-buffer LDS, 2-barrier
// K-loop, 4 blocks/CU. Epilogue: exp->bf16 tile into dead LDS -> coalesced
// dwordx4 stores. z is NOT computed here (R13/R14: any shfl+atomic rowsum
// in gemm1 costs 60-130us; gemm2 derives z locally for free).
__global__ __launch_bounds__(256, 4)
void gemm1k(const u16* __restrict__ A, const u16* __restrict__ B,
            u16* __restrict__ P, int nt,
            size_t Bb_str, size_t Cb_str, int gx, int gy) {
  __shared__ u16 lds[16384];   // A tile @0, B tile @8192; epilogue: 128x128 u16

  const int nwg = gx * gy * gridDim.z;
  const int orig = blockIdx.x + gx * (blockIdx.y + gy * blockIdx.z);
  const int cpx = nwg >> 3;
  const int nid = (orig & 7) * cpx + (orig >> 3);
  const int bxi = nid % gx;
  const int byi = (nid / gx) % gy;
  const int bzi = nid / (gx * gy);
  const int m0 = byi * 128, n0 = bxi * 128;

  const int tid = threadIdx.x;
  const int l = tid & 63;
  const int w = tid >> 6;
  const int wy = w >> 1, wx = w & 1;

  // staging (write side; inverse-swizzled global source)
  const int rowS = tid >> 3;
  const int cS = ((tid & 7) << 4) ^ ((rowS & 7) << 4);
  const u16* srcA0 = A + (size_t)(m0 + rowS) * 512 + (cS >> 1);
  const u16* srcB0 = B + (size_t)bzi * Bb_str + (size_t)(n0 + rowS) * 512 + (cS >> 1);
  const size_t rsk = (size_t)32 * 512;

  // read side (swizzled ds_read addresses)
  const int fr = l & 15;
  const int X = (fr & 7) << 4;
  const int kb = (l >> 4) << 4;
  const int swz0 = (kb ^ X) >> 1;
  const int swz1 = ((64 + kb) ^ X) >> 1;
  const int aRow = (wy * 64 + fr) * 64;
  const int bRow = (wx * 64 + fr) * 64;

  f32x4 acc[4][4] = {};

  for (int t = 0; t < nt; ++t) {
#pragma unroll
    for (int j = 0; j < 4; j++) {
      gl_lds16(srcA0 + j * rsk + t * 64, &lds[tid * 8 + j * 2048]);
      gl_lds16(srcB0 + j * rsk + t * 64, &lds[8192 + tid * 8 + j * 2048]);
    }
    __syncthreads();
#pragma unroll
    for (int ks = 0; ks < 2; ks++) {
      const int swz = ks ? swz1 : swz0;
      bf16x8 bfr[4], afr[4];
#pragma unroll
      for (int n = 0; n < 4; n++) bfr[n] = *(const bf16x8*)&lds[8192 + bRow + n * 1024 + swz];
#pragma unroll
      for (int m = 0; m < 4; m++) afr[m] = *(const bf16x8*)&lds[aRow + m * 1024 + swz];
#pragma unroll
      for (int m = 0; m < 4; m++)
#pragma unroll
        for (int n = 0; n < 4; n++)
          acc[m][n] = __builtin_amdgcn_mfma_f32_16x16x32_bf16(
              afr[m], bfr[n], acc[m][n], 0, 0, 0);
    }
    __syncthreads();
  }

  // ---- epilogue (R12-exact): exp -> bf16 tile in LDS -> coalesced stores ----
  const int rq = (l >> 4) * 4;  // C/D: col=lane&15, row=(lane>>4)*4+reg
#pragma unroll
  for (int m = 0; m < 4; m++) {
    const int lr0 = wy * 64 + m * 16 + rq;
#pragma unroll
    for (int n = 0; n < 4; n++) {
      const int lc = wx * 64 + n * 16 + fr;
#pragma unroll
      for (int r = 0; r < 4; r++)
        lds[(lr0 + r) * 128 + lc] = f2bf(__expf(acc[m][n][r]));
    }
  }
  __syncthreads();
  u16* Pb = P + (size_t)bzi * Cb_str;
#pragma unroll
  for (int k = 0; k < 8; k++) {
    const int row = k * 16 + (tid >> 4);
    const int cu = (tid & 15) * 8;
    *(uint4*)&Pb[(size_t)(m0 + row) * 2048 + n0 + cu] = *(const uint4*)&lds[row * 128 + cu];
  }
}

// ---------------- gemm2: out[b] = (P[b] @ XT_b^T) / z, z computed IN-BLOCK ----------------
// R14 main loop. Each block covers the FULL K=2048 = the whole P row, so
// rowsum(P) is derivable locally from the A-fragments: wx==0 waves (uniform
// branch) accumulate zp[m] += sum(afr[m]) on the idle VALU pipe; after the
// K-loop, 2 shfl_xor fold the 4 k-lanes and 1/z lands in rz_lds. No z array,
// no atomics, no extra kernel.
__global__ __launch_bounds__(256, 4)
void gemm2k(const u16* __restrict__ A, const u16* __restrict__ B,
            float* __restrict__ Cout, int Kstride, int nt, int N,
            size_t Ab_str, size_t Bb_str, size_t Cb_str, int gx, int gy) {
  __shared__ u16 lds[16384];
  __shared__ float rz_lds[128];

  const int nwg = gx * gy * gridDim.z;
  const int orig = blockIdx.x + gx * (blockIdx.y + gy * blockIdx.z);
  const int cpx = nwg >> 3;
  const int nid = (orig & 7) * cpx + (orig >> 3);
  const int bxi = nid % gx;
  const int byi = (nid / gx) % gy;
  const int bzi = nid / (gx * gy);
  const int m0 = byi * 128, n0 = bxi * 128;

  const u16* Ab = A + (size_t)bzi * Ab_str;
  const u16* Bb = B + (size_t)bzi * Bb_str;

  const int tid = threadIdx.x;
  const int l = tid & 63;
  const int w = tid >> 6;
  const int wy = w >> 1, wx = w & 1;

  const int rowS = tid >> 3;
  const int cS = ((tid & 7) << 4) ^ ((rowS & 7) << 4);
  const u16* srcA0 = Ab + (size_t)(m0 + rowS) * Kstride + (cS >> 1);
  const u16* srcB0 = Bb + (size_t)(n0 + rowS) * Kstride + (cS >> 1);
  const size_t rsk = (size_t)32 * Kstride;

  const int fr = l & 15;
  const int X = (fr & 7) << 4;
  const int kb = (l >> 4) << 4;
  const int swz0 = (kb ^ X) >> 1;
  const int swz1 = ((64 + kb) ^ X) >> 1;
  const int aRow = (wy * 64 + fr) * 64;
  const int bRow = (wx * 64 + fr) * 64;

  f32x4 acc[4][4] = {};
  float zp[4] = {0.f, 0.f, 0.f, 0.f};

  for (int t = 0; t < nt; ++t) {
#pragma unroll
    for (int j = 0; j < 4; j++) {
      gl_lds16(srcA0 + j * rsk + t * 64, &lds[tid * 8 + j * 2048]);
      gl_lds16(srcB0 + j * rsk + t * 64, &lds[8192 + tid * 8 + j * 2048]);
    }
    __syncthreads();
#pragma unroll
    for (int ks = 0; ks < 2; ks++) {
      const int swz = ks ? swz1 : swz0;
      bf16x8 bfr[4], afr[4];
#pragma unroll
      for (int n = 0; n < 4; n++) bfr[n] = *(const bf16x8*)&lds[8192 + bRow + n * 1024 + swz];
#pragma unroll
      for (int m = 0; m < 4; m++) afr[m] = *(const bf16x8*)&lds[aRow + m * 1024 + swz];
#pragma unroll
      for (int m = 0; m < 4; m++)
#pragma unroll
        for (int n = 0; n < 4; n++)
          acc[m][n] = __builtin_amdgcn_mfma_f32_16x16x32_bf16(
              afr[m], bfr[n], acc[m][n], 0, 0, 0);
      if (wx == 0) {  // wave-uniform; idle-VALU rowsum accumulation
#pragma unroll
        for (int m = 0; m < 4; m++) zp[m] += sumfrag(afr[m]);
      }
    }
    __syncthreads();
  }

  // fold k-lanes (l, l^16, l^32, l^48) -> full rowsum; publish 1/z
  if (wx == 0) {
#pragma unroll
    for (int m = 0; m < 4; m++) {
      zp[m] += __shfl_xor(zp[m], 16);
      zp[m] += __shfl_xor(zp[m], 32);
      if (l < 16) rz_lds[wy * 64 + m * 16 + l] = 1.f / zp[m];
    }
  }
  __syncthreads();

  const int rq = (l >> 4) * 4;
#pragma unroll
  for (int m = 0; m < 4; m++) {
    const int lrow = wy * 64 + m * 16 + rq;
    const int grow = m0 + lrow;
#pragma unroll
    for (int n = 0; n < 4; n++) {
      const int col = n0 + wx * 64 + n * 16 + fr;
#pragma unroll
      for (int r = 0; r < 4; r++)
        Cout[(size_t)bzi * Cb_str + (size_t)(grow + r) * N + col] =
            acc[m][n][r] * rz_lds[lrow + r];
    }
  }
}

// B=8, L=2048, D=512, Y=8192
extern "C" void kernel_launch(void* const* d_in, const int* in_sizes, int n_in,
                              void* d_out, int out_size, void* d_ws, size_t ws_size,
                              hipStream_t stream) {
  const float* x = (const float*)d_in[0];   // [8][2048][512]
  const float* U = (const float*)d_in[1];   // [8192][512]
  if (n_in >= 2 && in_sizes[0] == 8192 * 512) {
    x = (const float*)d_in[1];
    U = (const float*)d_in[0];
  }
  float* out = (float*)d_out;               // [8][8192][512]
  char* ws = (char*)d_ws;

  // ws layout (bytes)
  u16* Ub = (u16*)ws;                       // 8 MiB
  u16* Xb = (u16*)(ws + 8388608);           // 16 MiB
  u16* XT = (u16*)(ws + 25165824);          // 16 MiB
  u16* P  = (u16*)(ws + 41943040);          // all-batch: 256 MiB
  const size_t need_all = 41943040ull + 268435456ull;

  cvt_bf16<<<4096, 256, 0, stream>>>(U, Ub, (8192 * 512) / 4);
  prep_x<<<dim3(16, 64, 8), 256, 0, stream>>>(x, Xb, XT);

  if (ws_size >= need_all) {
    // P[b] = exp(U @ x_b^T): M=8192, N=2048, K=512
    gemm1k<<<dim3(16, 64, 8), 256, 0, stream>>>(
        Ub, Xb, P, 8, (size_t)2048 * 512, (size_t)8192 * 2048, 16, 64);
    // out[b] = (P[b] @ XT_b^T) / rowsum(P[b]): M=8192, N=512, K=2048
    gemm2k<<<dim3(4, 64, 8), 256, 0, stream>>>(
        P, XT, out, 2048, 32, 512,
        (size_t)8192 * 2048, (size_t)512 * 2048, (size_t)8192 * 512, 4, 64);
  } else {
    // fallback: per-batch P (32 MiB)
    for (int b = 0; b < 8; b++) {
      gemm1k<<<dim3(16, 64, 1), 256, 0, stream>>>(
          Ub, Xb + (size_t)b * 2048 * 512, P, 8, 0, 0, 16, 64);
      gemm2k<<<dim3(4, 64, 1), 256, 0, stream>>>(
          P, XT + (size_t)b * 512 * 2048, out + (size_t)b * 8192 * 512,
          2048, 32, 512, 0, 0, 0, 4, 64);
    }
  }
}

// Round 16
// 357.702 us; speedup vs baseline: 1.2706x; 1.0003x over previous
//
#include <hip/hip_runtime.h>

typedef unsigned short u16;
typedef unsigned int u32;
typedef __attribute__((ext_vector_type(8))) short bf16x8;
typedef __attribute__((ext_vector_type(4))) float f32x4;

__device__ __forceinline__ u16 f2bf(float f) {
  u32 u = __float_as_uint(f);
  u32 r = (u + 0x7FFFu + ((u >> 16) & 1u)) >> 16;  // RTNE
  return (u16)r;
}

__device__ __forceinline__ void gl_lds16(const u16* g, u16* l) {
  __builtin_amdgcn_global_load_lds(
      (const __attribute__((address_space(1))) u32*)g,
      (__attribute__((address_space(3))) u32*)l, 16, 0, 0);
}

// ---------------- prep: U fp32 -> bf16 ----------------
__global__ __launch_bounds__(256) void cvt_bf16(const float* __restrict__ src,
                                                u16* __restrict__ dst, int n4) {
  int g = blockIdx.x * 256 + threadIdx.x;
  if (g < n4) {
    float4 v = ((const float4*)src)[g];
    ushort4 o;
    o.x = f2bf(v.x); o.y = f2bf(v.y); o.z = f2bf(v.z); o.w = f2bf(v.w);
    ((ushort4*)dst)[g] = o;
  }
}

// ---------------- prep: x fp32 -> Xb bf16 [b][l][d] and XT bf16 [b][d][l] ----------------
__global__ __launch_bounds__(256) void prep_x(const float* __restrict__ x,
                                              u16* __restrict__ Xb,
                                              u16* __restrict__ XT) {
  __shared__ u16 t[32][33];
  const int b = blockIdx.z;
  const int l0 = blockIdx.y * 32;
  const int d0 = blockIdx.x * 32;
  const int j = threadIdx.x & 31;
  const int t5 = threadIdx.x >> 5;
#pragma unroll
  for (int r = 0; r < 4; r++) {
    int i = r * 8 + t5;
    float v = x[((size_t)b * 2048 + l0 + i) * 512 + d0 + j];
    u16 h = f2bf(v);
    t[i][j] = h;
    Xb[((size_t)b * 2048 + l0 + i) * 512 + d0 + j] = h;
  }
  __syncthreads();
#pragma unroll
  for (int r = 0; r < 4; r++) {
    int i = r * 8 + t5;
    XT[((size_t)b * 512 + d0 + i) * 2048 + l0 + j] = t[j][i];
  }
}

// ---------------- gemm1: P[b] = bf16(exp(U @ x_b^T)), block-local z partials ----------------
// R12-exact main loop + epilogue (128x128 tile, BK=64, 4 waves 2x2, swizzled
// single-buffer LDS, 2-barrier K-loop, 4 blocks/CU; exp->bf16 tile in dead LDS
// -> coalesced dwordx4 stores). Tail (all post-barrier, atomic-free): rs[r]
// accumulated in the exp loop; after P-store, LDS is dead again -> padded
// [128][33] f32 scratch, 2 threads/row sum halves, 1 shfl, coalesced store to
// pz[bz][bxi][row] (unique writer per element -> no atomics, no zeroing).
__global__ __launch_bounds__(256, 4)
void gemm1k(const u16* __restrict__ A, const u16* __restrict__ B,
            u16* __restrict__ P, float* __restrict__ pz, int nt,
            size_t Bb_str, size_t Cb_str, int gx, int gy) {
  __shared__ u16 lds[16384];   // A tile @0, B tile @8192; epilogue: 128x128 u16

  const int nwg = gx * gy * gridDim.z;
  const int orig = blockIdx.x + gx * (blockIdx.y + gy * blockIdx.z);
  const int cpx = nwg >> 3;
  const int nid = (orig & 7) * cpx + (orig >> 3);
  const int bxi = nid % gx;
  const int byi = (nid / gx) % gy;
  const int bzi = nid / (gx * gy);
  const int m0 = byi * 128, n0 = bxi * 128;

  const int tid = threadIdx.x;
  const int l = tid & 63;
  const int w = tid >> 6;
  const int wy = w >> 1, wx = w & 1;

  // staging (write side; inverse-swizzled global source)
  const int rowS = tid >> 3;
  const int cS = ((tid & 7) << 4) ^ ((rowS & 7) << 4);
  const u16* srcA0 = A + (size_t)(m0 + rowS) * 512 + (cS >> 1);
  const u16* srcB0 = B + (size_t)bzi * Bb_str + (size_t)(n0 + rowS) * 512 + (cS >> 1);
  const size_t rsk = (size_t)32 * 512;

  // read side (swizzled ds_read addresses)
  const int fr = l & 15;
  const int X = (fr & 7) << 4;
  const int kb = (l >> 4) << 4;
  const int swz0 = (kb ^ X) >> 1;
  const int swz1 = ((64 + kb) ^ X) >> 1;
  const int aRow = (wy * 64 + fr) * 64;
  const int bRow = (wx * 64 + fr) * 64;

  f32x4 acc[4][4] = {};

  for (int t = 0; t < nt; ++t) {
#pragma unroll
    for (int j = 0; j < 4; j++) {
      gl_lds16(srcA0 + j * rsk + t * 64, &lds[tid * 8 + j * 2048]);
      gl_lds16(srcB0 + j * rsk + t * 64, &lds[8192 + tid * 8 + j * 2048]);
    }
    __syncthreads();
#pragma unroll
    for (int ks = 0; ks < 2; ks++) {
      const int swz = ks ? swz1 : swz0;
      bf16x8 bfr[4], afr[4];
#pragma unroll
      for (int n = 0; n < 4; n++) bfr[n] = *(const bf16x8*)&lds[8192 + bRow + n * 1024 + swz];
#pragma unroll
      for (int m = 0; m < 4; m++) afr[m] = *(const bf16x8*)&lds[aRow + m * 1024 + swz];
#pragma unroll
      for (int m = 0; m < 4; m++)
#pragma unroll
        for (int n = 0; n < 4; n++)
          acc[m][n] = __builtin_amdgcn_mfma_f32_16x16x32_bf16(
              afr[m], bfr[n], acc[m][n], 0, 0, 0);
    }
    __syncthreads();
  }

  // ---- epilogue: exp (+rs accumulate) -> bf16 tile in LDS -> coalesced stores ----
  const int rq = (l >> 4) * 4;  // C/D: col=lane&15, row=(lane>>4)*4+reg
  float rsv[4][4];
#pragma unroll
  for (int m = 0; m < 4; m++) {
    const int lr0 = wy * 64 + m * 16 + rq;
    float rs[4] = {0.f, 0.f, 0.f, 0.f};
#pragma unroll
    for (int n = 0; n < 4; n++) {
      const int lc = wx * 64 + n * 16 + fr;
#pragma unroll
      for (int r = 0; r < 4; r++) {
        const float e = __expf(acc[m][n][r]);
        lds[(lr0 + r) * 128 + lc] = f2bf(e);
        rs[r] += e;
      }
    }
#pragma unroll
    for (int r = 0; r < 4; r++) rsv[m][r] = rs[r];
  }
  __syncthreads();
  u16* Pb = P + (size_t)bzi * Cb_str;
#pragma unroll
  for (int k = 0; k < 8; k++) {
    const int row = k * 16 + (tid >> 4);
    const int cu = (tid & 15) * 8;
    *(uint4*)&Pb[(size_t)(m0 + row) * 2048 + n0 + cu] = *(const uint4*)&lds[row * 128 + cu];
  }
  __syncthreads();   // tile reads done -> LDS reusable as f32 scratch

  // ---- z partials: [128][33] padded LDS, 2 threads/row, 1 shfl, coalesced store ----
  float* pzl = (float*)lds;
#pragma unroll
  for (int m = 0; m < 4; m++)
#pragma unroll
    for (int r = 0; r < 4; r++)
      pzl[(wy * 64 + m * 16 + rq + r) * 33 + wx * 16 + fr] = rsv[m][r];
  __syncthreads();
  {
    const int row = tid >> 1, half = tid & 1;
    float s = 0.f;
#pragma unroll
    for (int j = 0; j < 16; j++) s += pzl[row * 33 + half * 16 + j];
    s += __shfl_xor(s, 1);
    if (!half) pz[((size_t)bzi * 16 + bxi) * 8192 + m0 + row] = s;
  }
}

// ---------------- gemm2: out[b] = (P[b] @ XT_b^T) / z, z = sum of 16 pz partials ----------------
// R14-exact main loop (no z work on the K-loop path). rz setup: 16 coalesced
// 512B loads before the loop, hidden under the first staging.
__global__ __launch_bounds__(256, 4)
void gemm2k(const u16* __restrict__ A, const u16* __restrict__ B,
            float* __restrict__ Cout, const float* __restrict__ pz,
            int Kstride, int nt, int N,
            size_t Ab_str, size_t Bb_str, size_t Cb_str, int gx, int gy) {
  __shared__ u16 lds[16384];
  __shared__ float rz_lds[128];

  const int nwg = gx * gy * gridDim.z;
  const int orig = blockIdx.x + gx * (blockIdx.y + gy * blockIdx.z);
  const int cpx = nwg >> 3;
  const int nid = (orig & 7) * cpx + (orig >> 3);
  const int bxi = nid % gx;
  const int byi = (nid / gx) % gy;
  const int bzi = nid / (gx * gy);
  const int m0 = byi * 128, n0 = bxi * 128;

  const u16* Ab = A + (size_t)bzi * Ab_str;
  const u16* Bb = B + (size_t)bzi * Bb_str;

  const int tid = threadIdx.x;
  const int l = tid & 63;
  const int w = tid >> 6;
  const int wy = w >> 1, wx = w & 1;

  const int rowS = tid >> 3;
  const int cS = ((tid & 7) << 4) ^ ((rowS & 7) << 4);
  const u16* srcA0 = Ab + (size_t)(m0 + rowS) * Kstride + (cS >> 1);
  const u16* srcB0 = Bb + (size_t)(n0 + rowS) * Kstride + (cS >> 1);
  const size_t rsk = (size_t)32 * Kstride;

  const int fr = l & 15;
  const int X = (fr & 7) << 4;
  const int kb = (l >> 4) << 4;
  const int swz0 = (kb ^ X) >> 1;
  const int swz1 = ((64 + kb) ^ X) >> 1;
  const int aRow = (wy * 64 + fr) * 64;
  const int bRow = (wx * 64 + fr) * 64;

  if (tid < 128) {
    const float* pzr = pz + (size_t)bzi * 16 * 8192 + m0 + tid;
    float s = 0.f;
#pragma unroll
    for (int j = 0; j < 16; j++) s += pzr[(size_t)j * 8192];
    rz_lds[tid] = 1.f / s;
  }

  f32x4 acc[4][4] = {};

  for (int t = 0; t < nt; ++t) {
#pragma unroll
    for (int j = 0; j < 4; j++) {
      gl_lds16(srcA0 + j * rsk + t * 64, &lds[tid * 8 + j * 2048]);
      gl_lds16(srcB0 + j * rsk + t * 64, &lds[8192 + tid * 8 + j * 2048]);
    }
    __syncthreads();
#pragma unroll
    for (int ks = 0; ks < 2; ks++) {
      const int swz = ks ? swz1 : swz0;
      bf16x8 bfr[4], afr[4];
#pragma unroll
      for (int n = 0; n < 4; n++) bfr[n] = *(const bf16x8*)&lds[8192 + bRow + n * 1024 + swz];
#pragma unroll
      for (int m = 0; m < 4; m++) afr[m] = *(const bf16x8*)&lds[aRow + m * 1024 + swz];
#pragma unroll
      for (int m = 0; m < 4; m++)
#pragma unroll
        for (int n = 0; n < 4; n++)
          acc[m][n] = __builtin_amdgcn_mfma_f32_16x16x32_bf16(
              afr[m], bfr[n], acc[m][n], 0, 0, 0);
    }
    __syncthreads();
  }

  const int rq = (l >> 4) * 4;
#pragma unroll
  for (int m = 0; m < 4; m++) {
    const int lrow = wy * 64 + m * 16 + rq;
    const int grow = m0 + lrow;
#pragma unroll
    for (int n = 0; n < 4; n++) {
      const int col = n0 + wx * 64 + n * 16 + fr;
#pragma unroll
      for (int r = 0; r < 4; r++)
        Cout[(size_t)bzi * Cb_str + (size_t)(grow + r) * N + col] =
            acc[m][n][r] * rz_lds[lrow + r];
    }
  }
}

// B=8, L=2048, D=512, Y=8192
extern "C" void kernel_launch(void* const* d_in, const int* in_sizes, int n_in,
                              void* d_out, int out_size, void* d_ws, size_t ws_size,
                              hipStream_t stream) {
  const float* x = (const float*)d_in[0];   // [8][2048][512]
  const float* U = (const float*)d_in[1];   // [8192][512]
  if (n_in >= 2 && in_sizes[0] == 8192 * 512) {
    x = (const float*)d_in[1];
    U = (const float*)d_in[0];
  }
  float* out = (float*)d_out;               // [8][8192][512]
  char* ws = (char*)d_ws;

  // ws layout (bytes)
  u16* Ub = (u16*)ws;                            // 8 MiB
  u16* Xb = (u16*)(ws + 8388608);                // 16 MiB
  u16* XT = (u16*)(ws + 25165824);               // 16 MiB
  u16* P  = (u16*)(ws + 41943040);               // all-batch: 256 MiB
  float* pz = (float*)(ws + 41943040 + 268435456);  // 8*16*8192*4 = 4 MiB
  const size_t need_all = 41943040ull + 268435456ull + 4194304ull;

  cvt_bf16<<<4096, 256, 0, stream>>>(U, Ub, (8192 * 512) / 4);
  prep_x<<<dim3(16, 64, 8), 256, 0, stream>>>(x, Xb, XT);

  if (ws_size >= need_all) {
    // P[b] = exp(U @ x_b^T), block-local rowsum partials -> pz
    gemm1k<<<dim3(16, 64, 8), 256, 0, stream>>>(
        Ub, Xb, P, pz, 8, (size_t)2048 * 512, (size_t)8192 * 2048, 16, 64);
    // out[b] = (P[b] @ XT_b^T) / z[b]: M=8192, N=512, K=2048
    gemm2k<<<dim3(4, 64, 8), 256, 0, stream>>>(
        P, XT, out, pz, 2048, 32, 512,
        (size_t)8192 * 2048, (size_t)512 * 2048, (size_t)8192 * 512, 4, 64);
  } else {
    // fallback: per-batch P (32 MiB); pz right after P
    u16* Pf = P;
    float* pzf = (float*)(ws + 41943040 + 33554432);
    for (int b = 0; b < 8; b++) {
      gemm1k<<<dim3(16, 64, 1), 256, 0, stream>>>(
          Ub, Xb + (size_t)b * 2048 * 512, Pf, pzf, 8, 0, 0, 16, 64);
      gemm2k<<<dim3(4, 64, 1), 256, 0, stream>>>(
          Pf, XT + (size_t)b * 512 * 2048, out + (size_t)b * 8192 * 512,
          pzf, 2048, 32, 512, 0, 0, 0, 4, 64);
    }
  }
}